// Round 1
// baseline (333.538 us; speedup 1.0000x reference)
//
#include <hip/hip_runtime.h>
#include <math.h>

#define B_    32
#define C_    128
#define N_    64
#define HID_  256
#define PIX_  4096
#define STEEP 50.0f
#define INV_PI 0.318309886183790671f
#define LDH   272  // LDS row pitch (u16): 32 h1 chunks (256) + 16 pad; x tile time-shares cols 128..255
#define LDX   72   // k5 pitch

typedef unsigned short u16;
typedef __attribute__((ext_vector_type(8))) short bf16x8;
typedef __attribute__((ext_vector_type(4))) float f32x4;

__device__ __forceinline__ u16 f2bf(float f) {
    unsigned int u = __builtin_bit_cast(unsigned int, f);
    unsigned int r = (u + 0x7FFFu + ((u >> 16) & 1u)) >> 16;
    return (u16)r;
}
__device__ __forceinline__ float bf2f(u16 h) {
    unsigned int u = ((unsigned int)h) << 16;
    return __builtin_bit_cast(float, u);
}
// swizzled LDS indices (chunk = 8 u16 = 16 B, rotated by row for bank spread)
__device__ __forceinline__ int h1_idx(int p, int k) {
    return p * LDH + (((k >> 3) + (p & 7)) & 31) * 8 + (k & 7);
}
__device__ __forceinline__ int x_idx(int p, int k) {
    return p * LDH + 128 + (((k >> 3) + (p & 7)) & 15) * 8 + (k & 7);
}

// ---------------- K0: init score buffers with biases ----------------
__global__ void k0_init(float* __restrict__ row_s, float* __restrict__ col_s,
                        const float* __restrict__ b_row, const float* __restrict__ b_col) {
    int i = blockIdx.x * 256 + threadIdx.x;
    if (i < B_ * N_) {
        row_s[i] = b_row[0];
        col_s[i] = b_col[0];
    }
}

// ---------------- Kprep: decompose weights into bf16 hi/lo ----------------
__global__ void k_prep(const float* __restrict__ w1, const float* __restrict__ w2,
                       u16* __restrict__ w1h, u16* __restrict__ w1l,
                       u16* __restrict__ w2h, u16* __restrict__ w2l) {
    int i = blockIdx.x * 256 + threadIdx.x;
    if (i < HID_ * C_) {
        float v = w1[i];
        u16 h = f2bf(v);
        w1h[i] = h;
        w1l[i] = f2bf(v - bf2f(h));
    } else {
        int j = i - HID_ * C_;
        if (j < HID_ * HID_) {
            float v = w2[j];
            u16 h = f2bf(v);
            w2h[j] = h;
            w2l[j] = f2bf(v - bf2f(h));
        }
    }
}

// ---------------- K12: fused conv1+conv2+scores, 32-pixel tiles, 4 blocks/CU ----------------
__global__ __launch_bounds__(256, 4) void k12_fused(
    const float* __restrict__ x,
    const u16* __restrict__ w1h, const u16* __restrict__ w1l,
    const float* __restrict__ b1,
    const u16* __restrict__ w2h, const u16* __restrict__ w2l,
    const float* __restrict__ b2, const float* __restrict__ w_row,
    const float* __restrict__ w_col,
    float* __restrict__ row_s, float* __restrict__ col_s) {
    __shared__ __align__(16) u16 Lh[32 * LDH];   // 17408 B (h1 hi / x hi staging)
    __shared__ __align__(16) u16 Ll[32 * LDH];   // 17408 B (h1 lo / x lo staging)
    __shared__ float col_red[32];
    __shared__ float row_red;

    const int t = threadIdx.x;
    const int l = t & 63, w = t >> 6;
    const int col = l & 15, q = l >> 4;
    const int hrow = blockIdx.x >> 1;
    const int half = blockIdx.x & 1;
    const int b = blockIdx.y;
    const float* xb = x + (size_t)b * C_ * PIX_ + hrow * 64 + half * 32;

    if (t < 32) col_red[t] = 0.f;
    if (t == 0) row_red = 0.f;

    // ---- stage x tile [32 p][128 c] -> swizzled cols 128..255 (one barrier) ----
    {
        const int pt = t & 7, ct = t >> 3;       // pt 0..7 (4 pixels each), ct 0..31
#pragma unroll
        for (int cc = 0; cc < 2; cc++) {
            const int c = cc * 64 + 2 * ct;
            float4 v0 = *(const float4*)&xb[(size_t)c * PIX_ + pt * 4];
            float4 v1 = *(const float4*)&xb[(size_t)(c + 1) * PIX_ + pt * 4];
            float a0[4] = {v0.x, v0.y, v0.z, v0.w};
            float a1[4] = {v1.x, v1.y, v1.z, v1.w};
#pragma unroll
            for (int j = 0; j < 4; j++) {
                int p = pt * 4 + j;
                u16 h0 = f2bf(a0[j]), h1v = f2bf(a1[j]);
                u16 l0 = f2bf(a0[j] - bf2f(h0)), l1 = f2bf(a1[j] - bf2f(h1v));
                int idx = x_idx(p, c);
                *(unsigned int*)&Lh[idx] = (unsigned int)h0 | ((unsigned int)h1v << 16);
                *(unsigned int*)&Ll[idx] = (unsigned int)l0 | ((unsigned int)l1 << 16);
            }
        }
    }
    __syncthreads();

    // ---- conv1: pipelined A (global) + B (LDS) ----
    f32x4 acc[4][2];
#pragma unroll
    for (int i = 0; i < 4; i++)
#pragma unroll
        for (int j = 0; j < 2; j++) acc[i][j] = (f32x4){0.f, 0.f, 0.f, 0.f};

    bf16x8 ah[4], al_[4];
#pragma unroll
    for (int mf = 0; mf < 4; mf++) {
        size_t ro = (size_t)(64 * w + 16 * mf + col) * C_ + q * 8;
        ah[mf] = *(const bf16x8*)&w1h[ro];
        al_[mf] = *(const bf16x8*)&w1l[ro];
    }
#pragma unroll
    for (int kc = 0; kc < 4; kc++) {
        bf16x8 bh[2], bl[2];
#pragma unroll
        for (int nt = 0; nt < 2; nt++) {
            int idx = x_idx(nt * 16 + col, kc * 32 + q * 8);
            bh[nt] = *(const bf16x8*)&Lh[idx];
            bl[nt] = *(const bf16x8*)&Ll[idx];
        }
        bf16x8 ahn[4], aln[4];
        const int kn = (kc + 1) & 3;
#pragma unroll
        for (int mf = 0; mf < 4; mf++) {
            size_t ro = (size_t)(64 * w + 16 * mf + col) * C_ + kn * 32 + q * 8;
            ahn[mf] = *(const bf16x8*)&w1h[ro];
            aln[mf] = *(const bf16x8*)&w1l[ro];
        }
#pragma unroll
        for (int mf = 0; mf < 4; mf++)
#pragma unroll
            for (int nt = 0; nt < 2; nt++) {
                acc[mf][nt] = __builtin_amdgcn_mfma_f32_16x16x32_bf16(ah[mf], bh[nt], acc[mf][nt], 0, 0, 0);
                acc[mf][nt] = __builtin_amdgcn_mfma_f32_16x16x32_bf16(ah[mf], bl[nt], acc[mf][nt], 0, 0, 0);
                acc[mf][nt] = __builtin_amdgcn_mfma_f32_16x16x32_bf16(al_[mf], bh[nt], acc[mf][nt], 0, 0, 0);
            }
#pragma unroll
        for (int mf = 0; mf < 4; mf++) { ah[mf] = ahn[mf]; al_[mf] = aln[mf]; }
    }

    // prefetch conv2's first A-frags before the barrier
    bf16x8 ah2[4], al2[4];
#pragma unroll
    for (int mf = 0; mf < 4; mf++) {
        size_t ro = (size_t)(64 * w + 16 * mf + col) * HID_ + q * 8;
        ah2[mf] = *(const bf16x8*)&w2h[ro];
        al2[mf] = *(const bf16x8*)&w2l[ro];
    }
    __syncthreads();   // all x-frag reads done; rows can be overwritten with h1

    // ---- conv1 epilogue: relu(acc+b1) -> swizzled h1 hi/lo ----
#pragma unroll
    for (int mf = 0; mf < 4; mf++) {
        int o = 64 * w + 16 * mf + q * 4;
        float bias[4];
#pragma unroll
        for (int r = 0; r < 4; r++) bias[r] = b1[o + r];
#pragma unroll
        for (int nt = 0; nt < 2; nt++) {
            int p = nt * 16 + col;
            u16 hh[4], ll[4];
#pragma unroll
            for (int r = 0; r < 4; r++) {
                float v = fmaxf(acc[mf][nt][r] + bias[r], 0.f);
                u16 h = f2bf(v);
                hh[r] = h;
                ll[r] = f2bf(v - bf2f(h));
            }
            int idx = h1_idx(p, o);
            *(unsigned long long*)&Lh[idx] =
                (unsigned long long)hh[0] | ((unsigned long long)hh[1] << 16) |
                ((unsigned long long)hh[2] << 32) | ((unsigned long long)hh[3] << 48);
            *(unsigned long long*)&Ll[idx] =
                (unsigned long long)ll[0] | ((unsigned long long)ll[1] << 16) |
                ((unsigned long long)ll[2] << 32) | ((unsigned long long)ll[3] << 48);
        }
    }
    __syncthreads();

    // ---- conv2: pipelined ----
    f32x4 acc2[4][2];
#pragma unroll
    for (int i = 0; i < 4; i++)
#pragma unroll
        for (int j = 0; j < 2; j++) acc2[i][j] = (f32x4){0.f, 0.f, 0.f, 0.f};

#pragma unroll
    for (int kc = 0; kc < 8; kc++) {
        bf16x8 bh[2], bl[2];
#pragma unroll
        for (int nt = 0; nt < 2; nt++) {
            int idx = h1_idx(nt * 16 + col, kc * 32 + q * 8);
            bh[nt] = *(const bf16x8*)&Lh[idx];
            bl[nt] = *(const bf16x8*)&Ll[idx];
        }
        bf16x8 ahn[4], aln[4];
        const int kn = (kc + 1) & 7;
#pragma unroll
        for (int mf = 0; mf < 4; mf++) {
            size_t ro = (size_t)(64 * w + 16 * mf + col) * HID_ + kn * 32 + q * 8;
            ahn[mf] = *(const bf16x8*)&w2h[ro];
            aln[mf] = *(const bf16x8*)&w2l[ro];
        }
#pragma unroll
        for (int mf = 0; mf < 4; mf++)
#pragma unroll
            for (int nt = 0; nt < 2; nt++) {
                acc2[mf][nt] = __builtin_amdgcn_mfma_f32_16x16x32_bf16(ah2[mf], bh[nt], acc2[mf][nt], 0, 0, 0);
                acc2[mf][nt] = __builtin_amdgcn_mfma_f32_16x16x32_bf16(ah2[mf], bl[nt], acc2[mf][nt], 0, 0, 0);
                acc2[mf][nt] = __builtin_amdgcn_mfma_f32_16x16x32_bf16(al2[mf], bh[nt], acc2[mf][nt], 0, 0, 0);
            }
#pragma unroll
        for (int mf = 0; mf < 4; mf++) { ah2[mf] = ahn[mf]; al2[mf] = aln[mf]; }
    }

    // ---- score epilogue ----
    float rpart = 0.f;
    float cpart[2] = {0.f, 0.f};
#pragma unroll
    for (int mf = 0; mf < 4; mf++) {
        int o = 64 * w + 16 * mf + q * 4;
#pragma unroll
        for (int r = 0; r < 4; r++) {
            float bias = b2[o + r];
            float wcv = w_col[(o + r) * N_ + hrow];
#pragma unroll
            for (int nt = 0; nt < 2; nt++) {
                int wc = nt * 16 + col;
                float v = fmaxf(acc2[mf][nt][r] + bias, 0.f);
                rpart += v * w_row[(o + r) * N_ + half * 32 + wc];
                cpart[nt] += v * wcv;
            }
        }
    }
#pragma unroll
    for (int off = 32; off; off >>= 1) rpart += __shfl_xor(rpart, off, 64);
    if (l == 0) atomicAdd(&row_red, rpart);
#pragma unroll
    for (int nt = 0; nt < 2; nt++) {
        float cp = cpart[nt];
        cp += __shfl_xor(cp, 16, 64);
        cp += __shfl_xor(cp, 32, 64);
        if (l < 16) atomicAdd(&col_red[nt * 16 + l], cp);
    }
    __syncthreads();
    if (t < 32) atomicAdd(&col_s[b * N_ + half * 32 + t], col_red[t]);
    if (t == 0) atomicAdd(&row_s[b * N_ + hrow], row_red);
}

// ---------------- K4: diff bitonic sort, register-resident P, shuffle-only ----------------
// Key identity: the 2x2 mix [[al,1-al],[1-al,al]] is symmetric, so for a lane
// holding column c of P (or score position c): new = al*self + (1-al)*partner,
// identical for both roles. alpha is computed redundantly per lane but is
// bitwise identical across the pair (diff = xb - xa either way).
__global__ __launch_bounds__(256) void k4_diffsort(const float* __restrict__ row_s,
                                                   const float* __restrict__ col_s,
                                                   u16* __restrict__ prow_h, u16* __restrict__ prow_l,
                                                   u16* __restrict__ pcol_h, u16* __restrict__ pcol_l) {
    const int t = threadIdx.x;
    const int lane = t & 63, w = t >> 6;
    const int which = blockIdx.x & 1;
    const int b = blockIdx.x >> 1;
    const float* sc = which ? col_s : row_s;
    u16* Ph = which ? pcol_h : prow_h;
    u16* Pl = which ? pcol_l : prow_l;

    float xv = sc[b * 64 + lane];
    float P[16];
#pragma unroll
    for (int r = 0; r < 16; r++) P[r] = ((w * 16 + r) == lane) ? 1.f : 0.f;

#pragma unroll
    for (int bl = 0; bl < 6; bl++) {
#pragma unroll
        for (int ly = 0; ly <= bl; ly++) {
            const int sh = bl - ly;
            const int m = 1 << sh;
            float xp = __shfl_xor(xv, m, 64);
            int lower = ((lane >> sh) & 1) ^ 1;            // lane is the low member of its pair
            int swp = (lane >> (bl + 1)) & 1;              // direction flip for this pair
            float diff = (lower ^ swp) ? (xp - xv) : (xv - xp);   // xb - xa (same value both lanes)
            float al = atanf(diff * STEEP) * INV_PI + 0.5f;
            xv = al * xv + (1.f - al) * xp;
#pragma unroll
            for (int r = 0; r < 16; r++) {
                float Pp = __shfl_xor(P[r], m, 64);
                P[r] = al * P[r] + (1.f - al) * Pp;
            }
        }
    }
#pragma unroll
    for (int r = 0; r < 16; r++) {
        float v = P[r];
        u16 h = f2bf(v);
        int row = w * 16 + r;
        Ph[(size_t)b * 4096 + row * 64 + lane] = h;
        Pl[(size_t)b * 4096 + row * 64 + lane] = f2bf(v - bf2f(h));
    }
}

// ---------------- K5: fused double permutation via MFMA ----------------
__global__ __launch_bounds__(256) void k5_permute(const float* __restrict__ x,
                                                  const u16* __restrict__ pcol_h,
                                                  const u16* __restrict__ pcol_l,
                                                  const u16* __restrict__ prow_h,
                                                  const u16* __restrict__ prow_l,
                                                  float* __restrict__ out) {
    __shared__ __align__(16) u16 Xh[64 * LDX];
    __shared__ __align__(16) u16 Xl[64 * LDX];
    __shared__ __align__(16) u16 Zh[64 * LDX];
    __shared__ __align__(16) u16 Zl[64 * LDX];
    const int t = threadIdx.x;
    const int l = t & 63, w = t >> 6;
    const int col = l & 15, q = l >> 4;
    const int b = blockIdx.y;
    const int cbase = blockIdx.x * 4;
    const int i0 = w * 16;

    const u16* pch = pcol_h + (size_t)b * 4096;
    const u16* pcl = pcol_l + (size_t)b * 4096;
    const u16* prh = prow_h + (size_t)b * 4096;
    const u16* prl = prow_l + (size_t)b * 4096;

    bf16x8 pcA_h[2], pcA_l[2];
#pragma unroll
    for (int ks = 0; ks < 2; ks++) {
        pcA_h[ks] = *(const bf16x8*)&pch[(i0 + col) * 64 + q * 8 + ks * 32];
        pcA_l[ks] = *(const bf16x8*)&pcl[(i0 + col) * 64 + q * 8 + ks * 32];
    }

    for (int ci = 0; ci < 4; ci++) {
        const int c = cbase + ci;
        const float* xc = x + ((size_t)b * C_ + c) * PIX_;
#pragma unroll
        for (int k = 0; k < 4; k++) {
            int f = t + k * 256;
            int rw = f >> 4, c4 = f & 15;
            float4 v = *(const float4*)&xc[f * 4];
            u16 h0 = f2bf(v.x), h1 = f2bf(v.y), h2 = f2bf(v.z), h3 = f2bf(v.w);
            ushort4 hv = {h0, h1, h2, h3};
            ushort4 lv = {f2bf(v.x - bf2f(h0)), f2bf(v.y - bf2f(h1)),
                          f2bf(v.z - bf2f(h2)), f2bf(v.w - bf2f(h3))};
            *(ushort4*)&Xh[rw * LDX + c4 * 4] = hv;
            *(ushort4*)&Xl[rw * LDX + c4 * 4] = lv;
        }
        __syncthreads();

        f32x4 acc[4];
#pragma unroll
        for (int nt = 0; nt < 4; nt++) acc[nt] = (f32x4){0.f, 0.f, 0.f, 0.f};
#pragma unroll
        for (int ks = 0; ks < 2; ks++) {
            bf16x8 ah = pcA_h[ks], al_ = pcA_l[ks];
#pragma unroll
            for (int nt = 0; nt < 4; nt++) {
                bf16x8 bh = *(const bf16x8*)&Xh[(nt * 16 + col) * LDX + q * 8 + ks * 32];
                bf16x8 bl = *(const bf16x8*)&Xl[(nt * 16 + col) * LDX + q * 8 + ks * 32];
                acc[nt] = __builtin_amdgcn_mfma_f32_16x16x32_bf16(ah, bh, acc[nt], 0, 0, 0);
                acc[nt] = __builtin_amdgcn_mfma_f32_16x16x32_bf16(ah, bl, acc[nt], 0, 0, 0);
                acc[nt] = __builtin_amdgcn_mfma_f32_16x16x32_bf16(al_, bh, acc[nt], 0, 0, 0);
            }
        }
#pragma unroll
        for (int nt = 0; nt < 4; nt++)
#pragma unroll
            for (int r = 0; r < 4; r++) {
                float v = acc[nt][r];
                u16 h = f2bf(v);
                int rw = i0 + q * 4 + r;
                Zh[rw * LDX + nt * 16 + col] = h;
                Zl[rw * LDX + nt * 16 + col] = f2bf(v - bf2f(h));
            }

        f32x4 acc2[4];
#pragma unroll
        for (int nt = 0; nt < 4; nt++) acc2[nt] = (f32x4){0.f, 0.f, 0.f, 0.f};
#pragma unroll
        for (int ks = 0; ks < 2; ks++) {
            bf16x8 ah = *(const bf16x8*)&Zh[(i0 + col) * LDX + q * 8 + ks * 32];
            bf16x8 al_ = *(const bf16x8*)&Zl[(i0 + col) * LDX + q * 8 + ks * 32];
#pragma unroll
            for (int nt = 0; nt < 4; nt++) {
                bf16x8 bh = *(const bf16x8*)&prh[(nt * 16 + col) * 64 + q * 8 + ks * 32];
                bf16x8 bl = *(const bf16x8*)&prl[(nt * 16 + col) * 64 + q * 8 + ks * 32];
                acc2[nt] = __builtin_amdgcn_mfma_f32_16x16x32_bf16(ah, bh, acc2[nt], 0, 0, 0);
                acc2[nt] = __builtin_amdgcn_mfma_f32_16x16x32_bf16(ah, bl, acc2[nt], 0, 0, 0);
                acc2[nt] = __builtin_amdgcn_mfma_f32_16x16x32_bf16(al_, bh, acc2[nt], 0, 0, 0);
            }
        }
        float* oc = out + ((size_t)b * C_ + c) * PIX_;
#pragma unroll
        for (int nt = 0; nt < 4; nt++)
#pragma unroll
            for (int r = 0; r < 4; r++)
                oc[(i0 + q * 4 + r) * 64 + nt * 16 + col] = acc2[nt][r];
        __syncthreads();
    }
}

extern "C" void kernel_launch(void* const* d_in, const int* in_sizes, int n_in,
                              void* d_out, int out_size, void* d_ws, size_t ws_size,
                              hipStream_t stream) {
    const float* x = (const float*)d_in[0];
    const float* w1 = (const float*)d_in[1];
    const float* b1 = (const float*)d_in[2];
    const float* w2 = (const float*)d_in[3];
    const float* b2 = (const float*)d_in[4];
    const float* w_row = (const float*)d_in[5];
    const float* b_row = (const float*)d_in[6];
    const float* w_col = (const float*)d_in[7];
    const float* b_col = (const float*)d_in[8];
    float* out = (float*)d_out;

    char* ws = (char*)d_ws;
    u16* w1h = (u16*)(ws);                   //  65536 B
    u16* w1l = (u16*)(ws + 65536);           //  65536 B
    u16* w2h = (u16*)(ws + 131072);          //  131072 B
    u16* w2l = (u16*)(ws + 262144);          //  131072 B
    float* row_s = (float*)(ws + 393216);    //  8192 B
    float* col_s = (float*)(ws + 401408);    //  8192 B
    u16* prow_h = (u16*)(ws + 409600);       //  262144 B
    u16* prow_l = (u16*)(ws + 671744);       //  262144 B
    u16* pcol_h = (u16*)(ws + 933888);       //  262144 B
    u16* pcol_l = (u16*)(ws + 1196032);      //  262144 B

    hipLaunchKernelGGL(k0_init, dim3(8), dim3(256), 0, stream, row_s, col_s, b_row, b_col);
    hipLaunchKernelGGL(k_prep, dim3(384), dim3(256), 0, stream, w1, w2, w1h, w1l, w2h, w2l);
    hipLaunchKernelGGL(k12_fused, dim3(128, 32), dim3(256), 0, stream,
                       x, w1h, w1l, b1, w2h, w2l, b2, w_row, w_col, row_s, col_s);
    hipLaunchKernelGGL(k4_diffsort, dim3(64), dim3(256), 0, stream,
                       row_s, col_s, prow_h, prow_l, pcol_h, pcol_l);
    hipLaunchKernelGGL(k5_permute, dim3(32, 32), dim3(256), 0, stream,
                       x, pcol_h, pcol_l, prow_h, prow_l, out);
}